// Round 1
// baseline (748.680 us; speedup 1.0000x reference)
//
#include <hip/hip_runtime.h>

#define BB 32
#define SS 4096
#define HH 1024
#define BS (BB * SS)
#define WPB 256                 // waves per batch
#define RPW (SS / WPB)          // rows per wave = 16
#define NWAVES (BB * WPB)       // 8192 waves
#define NBLOCKS (NWAVES / 4)    // 2048 blocks of 256

// Order-preserving float -> uint key (unsigned compare == float compare)
__device__ __forceinline__ unsigned fkey(float f) {
    unsigned u = __float_as_uint(f);
    return (u & 0x80000000u) ? ~u : (u | 0x80000000u);
}
__device__ __forceinline__ float funkey(unsigned k) {
    unsigned u = (k & 0x80000000u) ? (k ^ 0x80000000u) : ~k;
    return __uint_as_float(u);
}
__device__ __forceinline__ float dot4(float4 a, float4 w) {
    return a.x * w.x + a.y * w.y + a.z * w.z + a.w * w.w;
}

// v2: deferred-reduction GEMV.
// Streaming loop is pure load+FMA into per-lane partials p[16] (no cross-lane
// ops, no register rotation, no per-row serialization) -> compiler can pipeline
// loads several rows deep under the 128-VGPR cap from __launch_bounds__(256,4).
// All 16 wave reductions happen once, after the stream, with 16-way ILP.
__global__ __launch_bounds__(256, 4) void k_proj(
    const float* __restrict__ x, const int* __restrict__ mask,
    const float* __restrict__ W, const float* __restrict__ bvec,
    float* __restrict__ h, unsigned* __restrict__ mm)
{
    const int lane  = threadIdx.x & 63;
    const int gw    = blockIdx.x * 4 + (threadIdx.x >> 6);
    const int batch = gw >> 8;          // gw / WPB
    const int r0    = gw & (WPB - 1);   // starting row in batch
    const size_t rowBase = (size_t)batch * SS;

    // Prefetch the 16 mask words first; latency hides under the stream.
    int mk[RPW];
#pragma unroll
    for (int k = 0; k < RPW; ++k)
        mk[k] = mask[rowBase + r0 + (size_t)k * WPB];

    const float4* Wv = (const float4*)W;
    const float4 w0 = Wv[lane], w1 = Wv[64 + lane],
                 w2 = Wv[128 + lane], w3 = Wv[192 + lane];
    const float bval = bvec[0];

    // ---- pure streaming phase: 16 independent rows, per-lane partials ----
    float p[RPW];
#pragma unroll
    for (int k = 0; k < RPW; ++k) {
        const float4* xr = (const float4*)(x + (rowBase + r0 + (size_t)k * WPB) * HH);
        const float4 a0 = xr[lane],       a1 = xr[64 + lane],
                     a2 = xr[128 + lane], a3 = xr[192 + lane];
        p[k] = dot4(a0, w0) + dot4(a1, w1) + dot4(a2, w2) + dot4(a3, w3);
    }

    // ---- batched butterfly: 16 independent reduction chains (ILP) ----
#pragma unroll
    for (int off = 32; off >= 1; off >>= 1) {
#pragma unroll
        for (int k = 0; k < RPW; ++k)
            p[k] += __shfl_xor(p[k], off, 64);   // sum broadcast to all lanes
    }

    // ---- epilogue: store h, fold masked min/max, one atomic pair ----
    unsigned kmin = 0xFFFFFFFFu, kmax = 0u;
#pragma unroll
    for (int k = 0; k < RPW; ++k) {
        const float hv = p[k] + bval;
        if (lane == 0) h[rowBase + r0 + k * WPB] = hv;
        if (mk[k] != 0) {
            const unsigned key = fkey(hv);
            kmin = min(kmin, key); kmax = max(kmax, key);
        }
    }
    if (lane == 0) {
        atomicMin(&mm[batch], kmin);        // device-scope: XCD-safe
        atomicMax(&mm[BB + batch], kmax);
    }
}

// out = mask ? (h - hmin)/(hmax - hmin) : 0   (mean/std cancel algebraically)
__global__ __launch_bounds__(256) void k_final(
    const float* __restrict__ h, const int* __restrict__ mask,
    const unsigned* __restrict__ mm, float* __restrict__ out)
{
    const int i = blockIdx.x * 256 + threadIdx.x;
    if (i >= BS) return;
    const int batch = i >> 12;
    const float hmin = funkey(mm[batch]);
    const float hmax = funkey(mm[BB + batch]);
    const float inv = 1.0f / (hmax - hmin);
    const float v = (h[i] - hmin) * inv;
    out[i] = (mask[i] != 0) ? v : 0.0f;
}

extern "C" void kernel_launch(void* const* d_in, const int* in_sizes, int n_in,
                              void* d_out, int out_size, void* d_ws, size_t ws_size,
                              hipStream_t stream) {
    const float* x    = (const float*)d_in[0];
    const int*   mask = (const int*)d_in[1];
    const float* W    = (const float*)d_in[2];
    const float* bv   = (const float*)d_in[3];
    float* out = (float*)d_out;

    float*    h  = (float*)d_ws;                                   // BS floats
    unsigned* mm = (unsigned*)((char*)d_ws + (size_t)BS * 4);      // 2*BB uints

    hipMemsetAsync(mm, 0xFF, BB * sizeof(unsigned), stream);       // min slots
    hipMemsetAsync(mm + BB, 0x00, BB * sizeof(unsigned), stream);  // max slots

    k_proj<<<NBLOCKS, 256, 0, stream>>>(x, mask, W, bv, h, mm);
    k_final<<<(BS + 255) / 256, 256, 0, stream>>>(h, mask, mm, out);
}

// Round 2
// 684.200 us; speedup vs baseline: 1.0942x; 1.0942x over previous
//
#include <hip/hip_runtime.h>

#define BB 32
#define SS 4096
#define HH 1024
#define BS (BB * SS)            // 131072 rows total

// Order-preserving float -> uint key (unsigned compare == float compare)
__device__ __forceinline__ unsigned fkey(float f) {
    unsigned u = __float_as_uint(f);
    return (u & 0x80000000u) ? ~u : (u | 0x80000000u);
}
__device__ __forceinline__ float funkey(unsigned k) {
    unsigned u = (k & 0x80000000u) ? (k ^ 0x80000000u) : ~k;
    return __uint_as_float(u);
}
__device__ __forceinline__ float dot4(float4 a, float4 w) {
    return a.x * w.x + a.y * w.y + a.z * w.z + a.w * w.w;
}

// v3: one row per wave, no loop, minimal registers (~40 VGPR -> 8 waves/SIMD).
// Per wave: 4 independent dwordx4 loads (4 KB in flight), one vmcnt wait,
// 16 FMAs, 6-step butterfly, single store. 32 waves/CU * 4 KB = 128 KB
// outstanding per CU -- far above the ~9 KB Little's-law requirement.
// No atomics, no workspace init needed.
__global__ __launch_bounds__(256, 8) void k_proj(
    const float* __restrict__ x, const float* __restrict__ W,
    const float* __restrict__ bvec, float* __restrict__ h)
{
    const int lane = threadIdx.x & 63;
    const int row  = blockIdx.x * 4 + (threadIdx.x >> 6);   // 0..BS-1

    const float4* xr = (const float4*)(x + (size_t)row * HH);
    const float4 a0 = xr[lane],       a1 = xr[64 + lane],
                 a2 = xr[128 + lane], a3 = xr[192 + lane];

    const float4* Wv = (const float4*)W;                    // 4 KB, L2-hot
    const float4 w0 = Wv[lane],       w1 = Wv[64 + lane],
                 w2 = Wv[128 + lane], w3 = Wv[192 + lane];

    float acc = dot4(a0, w0) + dot4(a1, w1) + dot4(a2, w2) + dot4(a3, w3);
#pragma unroll
    for (int off = 32; off >= 1; off >>= 1)
        acc += __shfl_xor(acc, off, 64);

    if (lane == 0) h[row] = acc + bvec[0];
}

// Per-batch masked min/max over h (1 MB total input) -> mm[64].
// Unconditional writes: no init memsets, no atomics.
__global__ __launch_bounds__(256) void k_minmax(
    const float* __restrict__ h, const int* __restrict__ mask,
    unsigned* __restrict__ mm)
{
    const int batch = blockIdx.x;            // 32 blocks
    const int t = threadIdx.x;
    const size_t base = (size_t)batch * SS;

    unsigned kmin = 0xFFFFFFFFu, kmax = 0u;
    for (int i = t; i < SS; i += 256) {
        if (mask[base + i] != 0) {
            const unsigned k = fkey(h[base + i]);
            kmin = min(kmin, k); kmax = max(kmax, k);
        }
    }
#pragma unroll
    for (int off = 32; off >= 1; off >>= 1) {
        kmin = min(kmin, (unsigned)__shfl_xor((int)kmin, off, 64));
        kmax = max(kmax, (unsigned)__shfl_xor((int)kmax, off, 64));
    }
    __shared__ unsigned smin[4], smax[4];
    if ((t & 63) == 0) { smin[t >> 6] = kmin; smax[t >> 6] = kmax; }
    __syncthreads();
    if (t == 0) {
        const unsigned m0 = min(min(smin[0], smin[1]), min(smin[2], smin[3]));
        const unsigned M0 = max(max(smax[0], smax[1]), max(smax[2], smax[3]));
        mm[batch] = m0; mm[BB + batch] = M0;
    }
}

// out = mask ? (h - hmin)/(hmax - hmin) : 0   (mean/std cancel algebraically)
__global__ __launch_bounds__(256) void k_final(
    const float* __restrict__ h, const int* __restrict__ mask,
    const unsigned* __restrict__ mm, float* __restrict__ out)
{
    const int i = blockIdx.x * 256 + threadIdx.x;
    if (i >= BS) return;
    const int batch = i >> 12;
    const float hmin = funkey(mm[batch]);
    const float hmax = funkey(mm[BB + batch]);
    const float inv = 1.0f / (hmax - hmin);
    const float v = (h[i] - hmin) * inv;
    out[i] = (mask[i] != 0) ? v : 0.0f;
}

extern "C" void kernel_launch(void* const* d_in, const int* in_sizes, int n_in,
                              void* d_out, int out_size, void* d_ws, size_t ws_size,
                              hipStream_t stream) {
    const float* x    = (const float*)d_in[0];
    const int*   mask = (const int*)d_in[1];
    const float* W    = (const float*)d_in[2];
    const float* bv   = (const float*)d_in[3];
    float* out = (float*)d_out;

    float*    h  = (float*)d_ws;                                   // BS floats
    unsigned* mm = (unsigned*)((char*)d_ws + (size_t)BS * 4);      // 2*BB uints

    k_proj<<<BS / 4, 256, 0, stream>>>(x, W, bv, h);
    k_minmax<<<BB, 256, 0, stream>>>(h, mask, mm);
    k_final<<<(BS + 255) / 256, 256, 0, stream>>>(h, mask, mm, out);
}